// Round 4
// baseline (640.613 us; speedup 1.0000x reference)
//
#include <hip/hip_runtime.h>

#define VOCAB  82
#define EMBED  256
#define HIDDEN 128
#define BATCH  256
#define SEQ    512
#define KX     (HIDDEN + EMBED)   // 384 columns in each gate weight

// Gate order everywhere: g=0 -> f (W_f), g=1 -> o (W_o), g=2 -> c_tilde (W_c)
// Gv layout: [VOCAB][3][HIDDEN] = per-token x-part of each gate pre-activation.
// Static device buffer (126 KB) instead of d_ws: removes any dependence on ws_size.
__device__ __align__(16) float Gv_buf[VOCAB * 3 * HIDDEN];

__device__ __forceinline__ float fast_sigmoid(float x) {
    return 1.f / (1.f + __expf(-x));
}
__device__ __forceinline__ float fast_tanh(float x) {
    x = fminf(fmaxf(x, -15.f), 15.f);   // tanh(15) == 1.0f in fp32; avoids inf/inf
    float e = __expf(2.f * x);
    return (e - 1.f) / (e + 1.f);       // abs err ~1e-7
}

// Prologue: Gv[v][g][r] = dot(emb[v][:], W_g[r][HIDDEN:HIDDEN+EMBED])
__global__ __launch_bounds__(384, 2)
void gv_prologue(const float* __restrict__ emb,
                 const float* __restrict__ Wf,
                 const float* __restrict__ Wc,
                 const float* __restrict__ Wo) {
    const int v   = blockIdx.x;
    const int tid = threadIdx.x;        // 0..383
    const int g   = tid >> 7;
    const int r   = tid & 127;

    __shared__ __align__(16) float e_lds[EMBED];
    if (tid < EMBED) e_lds[tid] = emb[(size_t)v * EMBED + tid];
    __syncthreads();

    const float* Wg = (g == 0) ? Wf : (g == 1) ? Wo : Wc;
    const float4* wr = (const float4*)(Wg + (size_t)r * KX + HIDDEN);
    const float4* ev = (const float4*)e_lds;
    float a0 = 0.f, a1 = 0.f, a2 = 0.f, a3 = 0.f;
#pragma unroll
    for (int i = 0; i < EMBED / 4; ++i) {
        float4 w4 = wr[i];
        float4 e4 = ev[i];
        a0 += w4.x * e4.x;
        a1 += w4.y * e4.y;
        a2 += w4.z * e4.z;
        a3 += w4.w * e4.w;
    }
    Gv_buf[(size_t)v * (3 * HIDDEN) + tid] = (a0 + a1) + (a2 + a3);
}

// Main recurrence: one workgroup per batch row (256 WGs ~ 256 CUs).
// Thread tid=(g,r) owns gate g, output row r; W_h row kept in 128 VGPRs.
__global__ __launch_bounds__(384, 2)
void lstm_main(const int* __restrict__ tokens,
               const float* __restrict__ Wf,
               const float* __restrict__ Wc,
               const float* __restrict__ Wo,
               const float* __restrict__ clfW,
               const float* __restrict__ clfb,
               float* __restrict__ out) {
    const int b   = blockIdx.x;
    const int tid = threadIdx.x;        // 0..383
    const int g   = tid >> 7;
    const int r   = tid & 127;

    __shared__ __align__(16) float h_lds[HIDDEN];
    __shared__ float gates[3][HIDDEN];
    __shared__ int   tok[SEQ];

    // Load this thread's h-part weight row into registers (fully unrolled -> stays in VGPRs).
    const float* Wg = (g == 0) ? Wf : (g == 1) ? Wo : Wc;
    const float4* wr4 = (const float4*)(Wg + (size_t)r * KX);   // cols 0..127 = h part
    float w[HIDDEN];
#pragma unroll
    for (int i = 0; i < HIDDEN / 4; ++i) {
        float4 w4 = wr4[i];
        w[4 * i + 0] = w4.x;
        w[4 * i + 1] = w4.y;
        w[4 * i + 2] = w4.z;
        w[4 * i + 3] = w4.w;
    }

    for (int i = tid; i < SEQ; i += 384) tok[i] = tokens[(size_t)b * SEQ + i];
    if (tid < HIDDEN) h_lds[tid] = 0.f;
    float c = 0.f;                      // cell state, valid for tid < 128
    __syncthreads();

    const size_t GATE0 = (size_t)BATCH * VOCAB;            // logits block size
    const size_t GSZ   = (size_t)SEQ * BATCH * HIDDEN;     // one gate stack
    float* gout = out + GATE0 + (size_t)g * GSZ + (size_t)b * HIDDEN + r;

    float val = 0.f;
    for (int t = 0; t < SEQ; ++t) {
        const int tk = tok[t];
        const float gx = Gv_buf[tk * (3 * HIDDEN) + tid];  // L2-resident, issued early

        const float4* h4 = (const float4*)h_lds;           // same-address broadcast reads
        float a0 = 0.f, a1 = 0.f, a2 = 0.f, a3 = 0.f;
#pragma unroll
        for (int i = 0; i < HIDDEN / 4; ++i) {
            float4 hv = h4[i];
            a0 += w[4 * i + 0] * hv.x;
            a1 += w[4 * i + 1] * hv.y;
            a2 += w[4 * i + 2] * hv.z;
            a3 += w[4 * i + 3] * hv.w;
        }
        const float pre = (a0 + a1) + (a2 + a3) + gx;
        val = (g == 2) ? fast_tanh(pre) : fast_sigmoid(pre);  // wave-uniform branch
        gates[g][r] = val;
        __syncthreads();                                   // barrier 1: gates ready
        if (tid < HIDDEN) {
            const float f  = gates[0][r];
            const float o  = gates[1][r];
            const float ct = gates[2][r];
            c = f * c + (1.f - f) * ct;                    // coupled gate
            h_lds[r] = o * fast_tanh(c);
        }
        __syncthreads();                                   // barrier 2: h ready
        // Store AFTER barrier 2 so the vmcnt drain overlaps next step's dot product.
        gout[(size_t)t * (BATCH * HIDDEN)] = val;
    }

    // Epilogue: logits[b][v] = h_T . clfW[v] + clfb[v]
    if (tid < VOCAB) {
        const float4* cw = (const float4*)(clfW + (size_t)tid * HIDDEN);
        const float4* h4 = (const float4*)h_lds;
        float a0 = 0.f, a1 = 0.f, a2 = 0.f, a3 = 0.f;
#pragma unroll
        for (int i = 0; i < HIDDEN / 4; ++i) {
            float4 wv = cw[i];
            float4 hv = h4[i];
            a0 += wv.x * hv.x;
            a1 += wv.y * hv.y;
            a2 += wv.z * hv.z;
            a3 += wv.w * hv.w;
        }
        out[(size_t)b * VOCAB + tid] = (a0 + a1) + (a2 + a3) + clfb[tid];
    }
}

extern "C" void kernel_launch(void* const* d_in, const int* in_sizes, int n_in,
                              void* d_out, int out_size, void* d_ws, size_t ws_size,
                              hipStream_t stream) {
    const int*   tokens = (const int*)  d_in[0];
    const float* emb    = (const float*)d_in[1];
    const float* Wf     = (const float*)d_in[2];
    const float* Wc     = (const float*)d_in[3];
    const float* Wo     = (const float*)d_in[4];
    const float* clfW   = (const float*)d_in[5];
    const float* clfb   = (const float*)d_in[6];
    float*       out    = (float*)d_out;

    gv_prologue<<<VOCAB, 384, 0, stream>>>(emb, Wf, Wc, Wo);
    lstm_main<<<BATCH, 384, 0, stream>>>(tokens, Wf, Wc, Wo, clfW, clfb, out);
}

// Round 5
// 563.349 us; speedup vs baseline: 1.1372x; 1.1372x over previous
//
#include <hip/hip_runtime.h>

#define VOCAB  82
#define EMBED  256
#define HIDDEN 128
#define BATCH  256
#define SEQ    512
#define KX     (HIDDEN + EMBED)   // 384 columns in each gate weight
#define SEG    36                 // padded LDS segment stride (32 data + 4 pad floats)

// Gate order: g=0 -> f (W_f), g=1 -> o (W_o), g=2 -> c_tilde (W_c)
// Gv layout: [VOCAB][3][HIDDEN] = per-token x-part of each gate pre-activation.
__device__ __align__(16) float Gv_buf[VOCAB * 3 * HIDDEN];

__device__ __forceinline__ float fast_sigmoid(float x) {
    return 1.f / (1.f + __expf(-x));
}
__device__ __forceinline__ float fast_tanh(float x) {
    x = fminf(fmaxf(x, -15.f), 15.f);
    float e = __expf(2.f * x);
    return (e - 1.f) / (e + 1.f);
}
// Quad-wide sum via DPP quad_perm (pure VALU, no LDS pipe).
// xor1 = quad_perm[1,0,3,2] = 0xB1 ; xor2 = quad_perm[2,3,0,1] = 0x4E
__device__ __forceinline__ float quad_sum(float x) {
    int y1 = __builtin_amdgcn_mov_dpp(__float_as_int(x), 0xB1, 0xF, 0xF, true);
    x = x + __int_as_float(y1);
    int y2 = __builtin_amdgcn_mov_dpp(__float_as_int(x), 0x4E, 0xF, 0xF, true);
    return x + __int_as_float(y2);   // all 4 lanes end with the identical sum
}

// Prologue: one block per (v,g); 128 threads = one output row each.
__global__ __launch_bounds__(128, 2)
void gv_prologue(const float* __restrict__ emb,
                 const float* __restrict__ Wf,
                 const float* __restrict__ Wc,
                 const float* __restrict__ Wo) {
    const int g = blockIdx.x % 3;
    const int v = blockIdx.x / 3;
    const int r = threadIdx.x;

    __shared__ __align__(16) float e_lds[EMBED];
    e_lds[r]       = emb[(size_t)v * EMBED + r];
    e_lds[r + 128] = emb[(size_t)v * EMBED + r + 128];
    __syncthreads();

    const float* Wg = (g == 0) ? Wf : (g == 1) ? Wo : Wc;
    const float4* wr = (const float4*)(Wg + (size_t)r * KX + HIDDEN);
    const float4* ev = (const float4*)e_lds;
    float a0 = 0.f, a1 = 0.f, a2 = 0.f, a3 = 0.f;
#pragma unroll
    for (int i = 0; i < EMBED / 4; ++i) {
        float4 w4 = wr[i];
        float4 e4 = ev[i];
        a0 += w4.x * e4.x;
        a1 += w4.y * e4.y;
        a2 += w4.z * e4.z;
        a3 += w4.w * e4.w;
    }
    Gv_buf[(size_t)v * 384 + g * 128 + r] = (a0 + a1) + (a2 + a3);
}

// Main recurrence: 256 blocks (1/CU) x 512 threads (8 waves, 2/SIMD).
// Thread = (r = tid>>2, q = tid&3): all 3 gates of row r, K-quarter q.
// Weights: float4-typed, constant-indexed arrays -> SROA keeps them in VGPRs.
__global__ __launch_bounds__(512, 2)
void lstm_main(const int* __restrict__ tokens,
               const float* __restrict__ Wf,
               const float* __restrict__ Wc,
               const float* __restrict__ Wo,
               const float* __restrict__ clfW,
               const float* __restrict__ clfb,
               float* __restrict__ out) {
    const int b   = blockIdx.x;
    const int tid = threadIdx.x;        // 0..511
    const int q   = tid & 3;            // K-quarter / gate-lane
    const int r   = tid >> 2;           // 0..127 output row

    // h double-buffer, 4 bank-padded segments of 32 floats (+4 pad) each.
    // Segment s holds h[32s..32s+31]; pad keeps the 4 quad-lane reads on
    // disjoint banks (q*36 floats -> bank offset 4q).
    __shared__ __align__(16) float hbuf[2][4 * SEG];
    __shared__ int tok[SEQ];

    float4 wf[8], wo[8], wc[8];
    {
        const float4* pf = (const float4*)(Wf + (size_t)r * KX + q * 32);
        const float4* po = (const float4*)(Wo + (size_t)r * KX + q * 32);
        const float4* pc = (const float4*)(Wc + (size_t)r * KX + q * 32);
#pragma unroll
        for (int i = 0; i < 8; ++i) { wf[i] = pf[i]; wo[i] = po[i]; wc[i] = pc[i]; }
    }

    tok[tid] = tokens[(size_t)b * SEQ + tid];        // 512 threads, 512 tokens
    if (tid < HIDDEN) hbuf[0][(tid >> 5) * SEG + (tid & 31)] = 0.f;
    float c = 0.f;                                   // replicated per quad lane
    __syncthreads();

    const size_t GATE0 = (size_t)BATCH * VOCAB;
    const size_t GSZ   = (size_t)SEQ * BATCH * HIDDEN;
    // lane q stores gate q (q<3); q==3 pointer is never dereferenced
    float* gout = out + GATE0 + (size_t)q * GSZ + (size_t)b * HIDDEN + r;

    for (int t = 0; t < SEQ; ++t) {
        const int p  = t & 1;
        const int tk = tok[t];
        // x-part for (gate=q, row=r); folded once per gate pre-reduce
        const float gx = (q < 3) ? Gv_buf[tk * 384 + q * 128 + r] : 0.f;

        const float4* hv4 = (const float4*)&hbuf[p][q * SEG];
        float pf = 0.f, po = 0.f, pc = 0.f;
#pragma unroll
        for (int i = 0; i < 8; ++i) {
            float4 h4 = hv4[i];
            pf += wf[i].x * h4.x; pf += wf[i].y * h4.y;
            pf += wf[i].z * h4.z; pf += wf[i].w * h4.w;
            po += wo[i].x * h4.x; po += wo[i].y * h4.y;
            po += wo[i].z * h4.z; po += wo[i].w * h4.w;
            pc += wc[i].x * h4.x; pc += wc[i].y * h4.y;
            pc += wc[i].z * h4.z; pc += wc[i].w * h4.w;
        }
        pf += (q == 0) ? gx : 0.f;
        po += (q == 1) ? gx : 0.f;
        pc += (q == 2) ? gx : 0.f;

        const float pre_f = quad_sum(pf);
        const float pre_o = quad_sum(po);
        const float pre_c = quad_sum(pc);

        // all 4 lanes compute identically (same inputs) -> c stays consistent
        const float f  = fast_sigmoid(pre_f);
        const float o  = fast_sigmoid(pre_o);
        const float ct = fast_tanh(pre_c);
        c = f * c + (1.f - f) * ct;
        const float h = o * fast_tanh(c);

        if (q == 0) hbuf[1 - p][(r >> 5) * SEG + (r & 31)] = h;
        __syncthreads();                 // single barrier: ping-pong h buffer
        // store AFTER the barrier so the vmcnt drain lands in the next step
        const float sval = (q == 0) ? f : (q == 1) ? o : ct;
        if (q < 3) gout[(size_t)t * (BATCH * HIDDEN)] = sval;
    }

    // Epilogue: logits[b][v] = h_T . clfW[v] + clfb[v]; h_T is in hbuf[0] (SEQ even)
    if (tid < 4 * VOCAB) {
        const int v = tid >> 2;
        const float4* cw  = (const float4*)(clfW + (size_t)v * HIDDEN + q * 32);
        const float4* hv4 = (const float4*)&hbuf[0][q * SEG];
        float a = 0.f;
#pragma unroll
        for (int i = 0; i < 8; ++i) {
            float4 w4 = cw[i];
            float4 h4 = hv4[i];
            a += w4.x * h4.x + w4.y * h4.y + w4.z * h4.z + w4.w * h4.w;
        }
        a = quad_sum(a);
        if (q == 0) out[(size_t)b * VOCAB + v] = a + clfb[v];
    }
}

extern "C" void kernel_launch(void* const* d_in, const int* in_sizes, int n_in,
                              void* d_out, int out_size, void* d_ws, size_t ws_size,
                              hipStream_t stream) {
    const int*   tokens = (const int*)  d_in[0];
    const float* emb    = (const float*)d_in[1];
    const float* Wf     = (const float*)d_in[2];
    const float* Wc     = (const float*)d_in[3];
    const float* Wo     = (const float*)d_in[4];
    const float* clfW   = (const float*)d_in[5];
    const float* clfb   = (const float*)d_in[6];
    float*       out    = (float*)d_out;

    gv_prologue<<<3 * VOCAB, 128, 0, stream>>>(emb, Wf, Wc, Wo);
    lstm_main<<<BATCH, 512, 0, stream>>>(tokens, Wf, Wc, Wo, clfW, clfb, out);
}

// Round 6
// 547.937 us; speedup vs baseline: 1.1691x; 1.0281x over previous
//
#include <hip/hip_runtime.h>

#define VOCAB  82
#define EMBED  256
#define HIDDEN 128
#define BATCH  256
#define SEQ    512
#define KX     (HIDDEN + EMBED)   // 384 columns in each gate weight
#define SEG    36                 // padded LDS segment stride (32 data + 4 pad floats)

// Gate order: g=0 -> f (W_f), g=1 -> o (W_o), g=2 -> c_tilde (W_c)
// Gv layout: [VOCAB][3][HIDDEN] = per-token x-part of each gate pre-activation.
__device__ __align__(16) float Gv_buf[VOCAB * 3 * HIDDEN];

__device__ __forceinline__ float fast_sigmoid(float x) {
    return 1.f / (1.f + __expf(-x));
}
__device__ __forceinline__ float fast_tanh(float x) {
    x = fminf(fmaxf(x, -15.f), 15.f);
    float e = __expf(2.f * x);
    return (e - 1.f) / (e + 1.f);
}
// Quad-wide sum via DPP quad_perm (pure VALU, no LDS pipe).
__device__ __forceinline__ float quad_sum(float x) {
    int y1 = __builtin_amdgcn_mov_dpp(__float_as_int(x), 0xB1, 0xF, 0xF, true);
    x = x + __int_as_float(y1);
    int y2 = __builtin_amdgcn_mov_dpp(__float_as_int(x), 0x4E, 0xF, 0xF, true);
    return x + __int_as_float(y2);   // all 4 lanes end with the identical sum
}
// Pin a value into a VGPR: an asm def is NOT rematerializable, so the RA
// cannot sink the originating load back into the loop (the round-4/5 bug).
#define PIN(x) asm volatile("" : "+v"(x))

// Prologue: one block per (v,g); 128 threads = one output row each.
__global__ __launch_bounds__(128, 2)
void gv_prologue(const float* __restrict__ emb,
                 const float* __restrict__ Wf,
                 const float* __restrict__ Wc,
                 const float* __restrict__ Wo) {
    const int g = blockIdx.x % 3;
    const int v = blockIdx.x / 3;
    const int r = threadIdx.x;

    __shared__ __align__(16) float e_lds[EMBED];
    e_lds[r]       = emb[(size_t)v * EMBED + r];
    e_lds[r + 128] = emb[(size_t)v * EMBED + r + 128];
    __syncthreads();

    const float* Wg = (g == 0) ? Wf : (g == 1) ? Wo : Wc;
    const float4* wr = (const float4*)(Wg + (size_t)r * KX + HIDDEN);
    const float4* ev = (const float4*)e_lds;
    float a0 = 0.f, a1 = 0.f, a2 = 0.f, a3 = 0.f;
#pragma unroll
    for (int i = 0; i < EMBED / 4; ++i) {
        float4 w4 = wr[i];
        float4 e4 = ev[i];
        a0 += w4.x * e4.x;
        a1 += w4.y * e4.y;
        a2 += w4.z * e4.z;
        a3 += w4.w * e4.w;
    }
    Gv_buf[(size_t)v * 384 + g * 128 + r] = (a0 + a1) + (a2 + a3);
}

// Main recurrence: 256 blocks (1/CU) x 512 threads (8 waves, 2/SIMD).
// Thread = (r = tid>>2, q = tid&3): all 3 gates of row r, K-quarter q.
// 96 weight floats pinned in VGPRs via PIN().
__global__ __launch_bounds__(512)
void lstm_main(const int* __restrict__ tokens,
               const float* __restrict__ Wf,
               const float* __restrict__ Wc,
               const float* __restrict__ Wo,
               const float* __restrict__ clfW,
               const float* __restrict__ clfb,
               float* __restrict__ out) {
    const int b   = blockIdx.x;
    const int tid = threadIdx.x;        // 0..511
    const int q   = tid & 3;            // K-quarter / gate-lane
    const int r   = tid >> 2;           // 0..127 output row

    __shared__ __align__(16) float hbuf[2][4 * SEG];
    __shared__ int tok[SEQ];

    float4 wf[8], wo[8], wc[8];
    {
        const float4* pf = (const float4*)(Wf + (size_t)r * KX + q * 32);
        const float4* po = (const float4*)(Wo + (size_t)r * KX + q * 32);
        const float4* pc = (const float4*)(Wc + (size_t)r * KX + q * 32);
#pragma unroll
        for (int i = 0; i < 8; ++i) { wf[i] = pf[i]; wo[i] = po[i]; wc[i] = pc[i]; }
#pragma unroll
        for (int i = 0; i < 8; ++i) {
            PIN(wf[i].x); PIN(wf[i].y); PIN(wf[i].z); PIN(wf[i].w);
            PIN(wo[i].x); PIN(wo[i].y); PIN(wo[i].z); PIN(wo[i].w);
            PIN(wc[i].x); PIN(wc[i].y); PIN(wc[i].z); PIN(wc[i].w);
        }
    }

    tok[tid] = tokens[(size_t)b * SEQ + tid];        // 512 threads, 512 tokens
    if (tid < HIDDEN) hbuf[0][(tid >> 5) * SEG + (tid & 31)] = 0.f;
    float c = 0.f;                                   // replicated per quad lane
    __syncthreads();

    const size_t GATE0 = (size_t)BATCH * VOCAB;
    const size_t GSZ   = (size_t)SEQ * BATCH * HIDDEN;
    float* gout = out + GATE0 + (size_t)q * GSZ + (size_t)b * HIDDEN + r;

    for (int t = 0; t < SEQ; ++t) {
        const int p  = t & 1;
        const int tk = tok[t];
        const float gx = (q < 3) ? Gv_buf[tk * 384 + q * 128 + r] : 0.f;

        const float4* hv4 = (const float4*)&hbuf[p][q * SEG];
        float pf = 0.f, po = 0.f, pc = 0.f;
#pragma unroll
        for (int i = 0; i < 8; ++i) {
            float4 h4 = hv4[i];
            pf += wf[i].x * h4.x; pf += wf[i].y * h4.y;
            pf += wf[i].z * h4.z; pf += wf[i].w * h4.w;
            po += wo[i].x * h4.x; po += wo[i].y * h4.y;
            po += wo[i].z * h4.z; po += wo[i].w * h4.w;
            pc += wc[i].x * h4.x; pc += wc[i].y * h4.y;
            pc += wc[i].z * h4.z; pc += wc[i].w * h4.w;
        }
        pf += (q == 0) ? gx : 0.f;
        po += (q == 1) ? gx : 0.f;
        pc += (q == 2) ? gx : 0.f;

        const float pre_f = quad_sum(pf);
        const float pre_o = quad_sum(po);
        const float pre_c = quad_sum(pc);

        const float f  = fast_sigmoid(pre_f);
        const float o  = fast_sigmoid(pre_o);
        const float ct = fast_tanh(pre_c);
        c = f * c + (1.f - f) * ct;
        const float h = o * fast_tanh(c);

        if (q == 0) hbuf[1 - p][(r >> 5) * SEG + (r & 31)] = h;
        __syncthreads();                 // single barrier: ping-pong h buffer
        const float sval = (q == 0) ? f : (q == 1) ? o : ct;
        if (q < 3) gout[(size_t)t * (BATCH * HIDDEN)] = sval;
    }

    // Epilogue: logits[b][v] = h_T . clfW[v] + clfb[v]; h_T is in hbuf[0]
    if (tid < 4 * VOCAB) {
        const int v = tid >> 2;
        const float4* cw  = (const float4*)(clfW + (size_t)v * HIDDEN + q * 32);
        const float4* hv4 = (const float4*)&hbuf[0][q * SEG];
        float a = 0.f;
#pragma unroll
        for (int i = 0; i < 8; ++i) {
            float4 w4 = cw[i];
            float4 h4 = hv4[i];
            a += w4.x * h4.x + w4.y * h4.y + w4.z * h4.z + w4.w * h4.w;
        }
        a = quad_sum(a);
        if (q == 0) out[(size_t)b * VOCAB + v] = a + clfb[v];
    }
}

extern "C" void kernel_launch(void* const* d_in, const int* in_sizes, int n_in,
                              void* d_out, int out_size, void* d_ws, size_t ws_size,
                              hipStream_t stream) {
    const int*   tokens = (const int*)  d_in[0];
    const float* emb    = (const float*)d_in[1];
    const float* Wf     = (const float*)d_in[2];
    const float* Wc     = (const float*)d_in[3];
    const float* Wo     = (const float*)d_in[4];
    const float* clfW   = (const float*)d_in[5];
    const float* clfb   = (const float*)d_in[6];
    float*       out    = (float*)d_out;

    gv_prologue<<<3 * VOCAB, 128, 0, stream>>>(emb, Wf, Wc, Wo);
    lstm_main<<<BATCH, 512, 0, stream>>>(tokens, Wf, Wc, Wo, clfW, clfb, out);
}